// Round 7
// baseline (432.142 us; speedup 1.0000x reference)
//
#include <hip/hip_runtime.h>
#include <hip/hip_bf16.h>

typedef __attribute__((ext_vector_type(8))) short          s16x8;
typedef __attribute__((ext_vector_type(8))) unsigned short u16x8;
typedef __attribute__((ext_vector_type(4))) float          f4;

__device__ __forceinline__ float bf2f(unsigned short u) {
    union { unsigned int i; float f; } x; x.i = ((unsigned int)u) << 16; return x.f;
}
__device__ __forceinline__ float blo(unsigned int w) {
    union { unsigned int i; float f; } x; x.i = w << 16; return x.f;
}
__device__ __forceinline__ float bhi(unsigned int w) {
    union { unsigned int i; float f; } x; x.i = w & 0xffff0000u; return x.f;
}
__device__ __forceinline__ unsigned short f2bf(float f) {
    __hip_bfloat16 h = __float2bfloat16(f);
    return *reinterpret_cast<unsigned short*>(&h);
}
__device__ __forceinline__ void gload_lds16(const void* g, void* l) {
    __builtin_amdgcn_global_load_lds(
        (const __attribute__((address_space(1))) unsigned int*)g,
        (__attribute__((address_space(3))) unsigned int*)l, 16, 0, 0);
}

// Convert the 4 weight matrices (each 512x512 fp32) to bf16, concatenated.
__global__ __launch_bounds__(256) void cvt_w4(const float* __restrict__ a,
                                              const float* __restrict__ b,
                                              const float* __restrict__ c,
                                              const float* __restrict__ d,
                                              unsigned short* __restrict__ o) {
    const int i   = (blockIdx.x * 256 + threadIdx.x) * 8;
    const int seg = i >> 18;
    const int off = i & 262143;
    const float* s = (seg == 0) ? a : (seg == 1) ? b : (seg == 2) ? c : d;
    f4 x0 = *(const f4*)(s + off);
    f4 x1 = *(const f4*)(s + off + 4);
    unsigned short t[8];
    t[0] = f2bf(x0[0]); t[1] = f2bf(x0[1]); t[2] = f2bf(x0[2]); t[3] = f2bf(x0[3]);
    t[4] = f2bf(x1[0]); t[5] = f2bf(x1[1]); t[6] = f2bf(x1[2]); t[7] = f2bf(x1[3]);
    *(u16x8*)(o + i) = *(u16x8*)t;
}

// OUT[m][n] = (sum_k A[m][k] * W[n][k] + bias[n]) * scale
// A-in-REGISTERS (per-wave-private fragments loaded straight from global;
// compiler pipelines them, no barrier interaction). LDS = W double-buffer
// only (2 x 32 KB). Counted vmcnt ledger, raw s_barrier, full-N blocks.
template <bool AF32, bool OF32>
__global__ __launch_bounds__(256, 2) void gemm_rA(const void* __restrict__ Ap,
                                                  const unsigned short* __restrict__ Wb,
                                                  const float* __restrict__ bias,
                                                  void* __restrict__ Outp,
                                                  float scale) {
    constexpr int KD = 512, BK = 32, NT = KD / BK;   // 16 K-tiles
    constexpr int WSZ = 512 * BK * 2;                // 32 KB per buffer
    extern __shared__ unsigned char lds[];           // 2*WSZ

    const int tid  = threadIdx.x;
    const int lane = tid & 63;
    const int w    = tid >> 6;            // wave -> cols [w*128, w*128+128)
    const size_t m0 = (size_t)blockIdx.x * 64;

    const float*          Af = (const float*)Ap;
    const unsigned short* Ab = (const unsigned short*)Ap;

    const int fr = lane & 15;             // frag row (A) / col (B/D)
    const int j4 = lane >> 4;             // k-slot 0..3 (k = j4*8 + e)

    f4 acc[4][8];
#pragma unroll
    for (int i = 0; i < 4; ++i)
#pragma unroll
        for (int j = 0; j < 8; ++j) acc[i][j] = (f4)(0.0f);

    auto stageW = [&](int t) {
        unsigned char* base = lds + (t & 1) * WSZ;
        const int kt = t * BK;
#pragma unroll
        for (int i = 0; i < 8; ++i) {
            const int f = i * 256 + tid;
            const int l = f ^ ((f >> 3) & 7);
            gload_lds16(Wb + (size_t)(l >> 2) * KD + kt + (l & 3) * 8,
                        base + f * 16);
        }
    };

    f4    aF0[4][2], aF1[4][2];
    s16x8 aB0[4],    aB1[4];

    auto loadA = [&](int t, f4 (&nf)[4][2], s16x8 (&nb)[4]) {
        const int kt = t * BK + j4 * 8;
#pragma unroll
        for (int mi = 0; mi < 4; ++mi) {
            if constexpr (AF32) {
                const float* p = Af + (m0 + mi * 16 + fr) * KD + kt;
                nf[mi][0] = *(const f4*)p;
                nf[mi][1] = *(const f4*)(p + 4);
            } else {
                nb[mi] = *(const s16x8*)(Ab + (m0 + mi * 16 + fr) * KD + kt);
            }
        }
    };

    auto body = [&](int t, f4 (&cf)[4][2], f4 (&nf)[4][2],
                    s16x8 (&cb)[4], s16x8 (&nb)[4]) {
        // ensure W(t) landed; leave A(t)+W(t+1) in flight
        if (t < NT - 1) {
            if constexpr (AF32) asm volatile("s_waitcnt vmcnt(16)" ::: "memory");
            else                asm volatile("s_waitcnt vmcnt(12)" ::: "memory");
        } else {
            if constexpr (AF32) asm volatile("s_waitcnt vmcnt(8)" ::: "memory");
            else                asm volatile("s_waitcnt vmcnt(4)" ::: "memory");
        }
        __builtin_amdgcn_s_barrier();
        __builtin_amdgcn_sched_barrier(0);

        unsigned char* base = lds + (t & 1) * WSZ;
        s16x8 af[4];
#pragma unroll
        for (int mi = 0; mi < 4; ++mi) {
            if constexpr (AF32) {
                unsigned short u[8];
#pragma unroll
                for (int e = 0; e < 4; ++e) u[e]     = f2bf(cf[mi][0][e]);
#pragma unroll
                for (int e = 0; e < 4; ++e) u[4 + e] = f2bf(cf[mi][1][e]);
                af[mi] = *(s16x8*)u;
            } else {
                af[mi] = cb[mi];
            }
        }
#pragma unroll
        for (int ni = 0; ni < 8; ++ni) {
            const int nrow = w * 128 + ni * 16 + fr;
            const int L = (nrow << 2) | j4;
            const int P = L ^ ((L >> 3) & 7);
            const s16x8 bf = *(const s16x8*)(base + (P << 4));
#pragma unroll
            for (int mi = 0; mi < 4; ++mi)
                acc[mi][ni] = __builtin_amdgcn_mfma_f32_16x16x32_bf16(
                    af[mi], bf, acc[mi][ni], 0, 0, 0);
        }
        __builtin_amdgcn_sched_barrier(0);
        __builtin_amdgcn_s_barrier();
        __builtin_amdgcn_sched_barrier(0);
        if (t + 1 < NT) loadA(t + 1, nf, nb);    // A first (newest-last order
        __builtin_amdgcn_sched_barrier(0);       //  keeps compiler A-wait at 8)
        if (t + 2 < NT) stageW(t + 2);
    };

    stageW(0);
    loadA(0, aF0, aB0);
    stageW(1);

#pragma unroll
    for (int tt = 0; tt < NT / 2; ++tt) {
        body(2 * tt,     aF0, aF1, aB0, aB1);
        body(2 * tt + 1, aF1, aF0, aB1, aB0);
    }

    const int rq = (lane >> 4) << 2;
#pragma unroll
    for (int ni = 0; ni < 8; ++ni) {
        const int   col = w * 128 + ni * 16 + fr;
        const float bv  = bias[col];
#pragma unroll
        for (int mi = 0; mi < 4; ++mi) {
            const size_t rbase = m0 + mi * 16 + rq;
#pragma unroll
            for (int r = 0; r < 4; ++r) {
                const float val = (acc[mi][ni][r] + bv) * scale;
                if constexpr (OF32)
                    ((float*)Outp)[(rbase + r) * KD + col] = val;
                else
                    ((unsigned short*)Outp)[(rbase + r) * KD + col] = f2bf(val);
            }
        }
    }
}

// LDS-tiled NAT: one block per (b, head, 16x16 pixel tile).
// Inner loops: u32 lo/hi bf16 unpack + 4-way split accumulators (ILP).
__global__ __launch_bounds__(256) void natt(const unsigned short* __restrict__ qh,
                                            const unsigned short* __restrict__ kh,
                                            const unsigned short* __restrict__ vh,
                                            const float* __restrict__ rpb,
                                            unsigned short* __restrict__ xout) {
    constexpr int LDK = 40;
    __shared__ unsigned short KV[484][LDK];
    __shared__ float Rs[169];

    const int tid = threadIdx.x;
    const int h   = blockIdx.z & 15;
    const int b   = blockIdx.z >> 4;
    const int x0  = blockIdx.x * 16;
    const int y0  = blockIdx.y * 16;
    const int ux0 = min(max(x0 - 3, 0), 106);
    const int uy0 = min(max(y0 - 3, 0), 106);
    const int tx  = tid & 15;
    const int ty  = tid >> 4;
    const int x   = x0 + tx;
    const int y   = y0 + ty;

    if (tid < 169) Rs[tid] = rpb[h * 169 + tid];

    const long imgbase = (long)b * 128 * 128;

#pragma unroll 2
    for (int kk = tid; kk < 484; kk += 256) {
        const int ky = uy0 + kk / 22;
        const int kx = ux0 + kk % 22;
        const unsigned short* src = kh + (imgbase + ky * 128 + kx) * 512 + h * 32;
#pragma unroll
        for (int j = 0; j < 4; ++j)
            *(u16x8*)&KV[kk][j * 8] = *(const u16x8*)(src + j * 8);
    }

    const long pix = imgbase + y * 128 + x;
    const unsigned short* qp = qh + pix * 512 + h * 32;
    float qv[32];
#pragma unroll
    for (int j = 0; j < 4; ++j) {
        u16x8 v = *(const u16x8*)(qp + j * 8);
#pragma unroll
        for (int e = 0; e < 8; ++e) qv[j * 8 + e] = bf2f(v[e]);
    }

    const int myy = min(max(y - 3, 0), 121) - uy0;
    const int myx = min(max(x - 3, 0), 121) - ux0;
    const int pbY = (y < 3) ? (6 - y) : ((y >= 125) ? (127 - y) : 3);
    const int pbX = (x < 3) ? (6 - x) : ((x >= 125) ? (127 - x) : 3);

    __syncthreads();

    float logit[49];
#pragma unroll
    for (int a = 0; a < 7; ++a) {
        const int rowk = (myy + a) * 22 + myx;
#pragma unroll
        for (int c = 0; c < 7; ++c) {
            const unsigned int* kp = (const unsigned int*)&KV[rowk + c][0];
            float s0 = 0.f, s1 = 0.f, s2 = 0.f, s3 = 0.f;
#pragma unroll
            for (int j = 0; j < 4; ++j) {
                const unsigned int w0 = kp[4 * j];
                const unsigned int w1 = kp[4 * j + 1];
                const unsigned int w2 = kp[4 * j + 2];
                const unsigned int w3 = kp[4 * j + 3];
                s0 = fmaf(qv[8 * j + 0], blo(w0), s0);
                s1 = fmaf(qv[8 * j + 1], bhi(w0), s1);
                s2 = fmaf(qv[8 * j + 2], blo(w1), s2);
                s3 = fmaf(qv[8 * j + 3], bhi(w1), s3);
                s0 = fmaf(qv[8 * j + 4], blo(w2), s0);
                s1 = fmaf(qv[8 * j + 5], bhi(w2), s1);
                s2 = fmaf(qv[8 * j + 6], blo(w3), s2);
                s3 = fmaf(qv[8 * j + 7], bhi(w3), s3);
            }
            logit[a * 7 + c] = ((s0 + s1) + (s2 + s3)) + Rs[(pbY + a) * 13 + pbX + c];
        }
    }

    float m = logit[0];
#pragma unroll
    for (int i = 1; i < 49; ++i) m = fmaxf(m, logit[i]);
    float sum = 0.f;
#pragma unroll
    for (int i = 0; i < 49; ++i) {
        float p = exp2f((logit[i] - m) * 1.4426950408889634f);
        logit[i] = p;
        sum += p;
    }
    const float rinv = 1.f / sum;
#pragma unroll
    for (int i = 0; i < 49; ++i) logit[i] *= rinv;

    __syncthreads();

#pragma unroll 2
    for (int kk = tid; kk < 484; kk += 256) {
        const int ky = uy0 + kk / 22;
        const int kx = ux0 + kk % 22;
        const unsigned short* src = vh + (imgbase + ky * 128 + kx) * 512 + h * 32;
#pragma unroll
        for (int j = 0; j < 4; ++j)
            *(u16x8*)&KV[kk][j * 8] = *(const u16x8*)(src + j * 8);
    }
    __syncthreads();

    float acc[32];
#pragma unroll
    for (int d = 0; d < 32; ++d) acc[d] = 0.f;
#pragma unroll
    for (int a = 0; a < 7; ++a) {
        const int rowk = (myy + a) * 22 + myx;
#pragma unroll
        for (int c = 0; c < 7; ++c) {
            const unsigned int* vp = (const unsigned int*)&KV[rowk + c][0];
            const float wgt = logit[a * 7 + c];
#pragma unroll
            for (int j = 0; j < 4; ++j) {
                const unsigned int w0 = vp[4 * j];
                const unsigned int w1 = vp[4 * j + 1];
                const unsigned int w2 = vp[4 * j + 2];
                const unsigned int w3 = vp[4 * j + 3];
                acc[8 * j + 0] = fmaf(wgt, blo(w0), acc[8 * j + 0]);
                acc[8 * j + 1] = fmaf(wgt, bhi(w0), acc[8 * j + 1]);
                acc[8 * j + 2] = fmaf(wgt, blo(w1), acc[8 * j + 2]);
                acc[8 * j + 3] = fmaf(wgt, bhi(w1), acc[8 * j + 3]);
                acc[8 * j + 4] = fmaf(wgt, blo(w2), acc[8 * j + 4]);
                acc[8 * j + 5] = fmaf(wgt, bhi(w2), acc[8 * j + 5]);
                acc[8 * j + 6] = fmaf(wgt, blo(w3), acc[8 * j + 6]);
                acc[8 * j + 7] = fmaf(wgt, bhi(w3), acc[8 * j + 7]);
            }
        }
    }

    unsigned short* op = xout + pix * 512 + h * 32;
#pragma unroll
    for (int j = 0; j < 4; ++j) {
        unsigned short t[8];
#pragma unroll
        for (int e = 0; e < 8; ++e) t[e] = f2bf(acc[j * 8 + e]);
        *(u16x8*)(op + j * 8) = *(u16x8*)t;
    }
}

extern "C" void kernel_launch(void* const* d_in, const int* in_sizes, int n_in,
                              void* d_out, int out_size, void* d_ws, size_t ws_size,
                              hipStream_t stream) {
    const float* q   = (const float*)d_in[0];
    const float* k   = (const float*)d_in[1];
    const float* v   = (const float*)d_in[2];
    const float* wq  = (const float*)d_in[3];
    const float* bq  = (const float*)d_in[4];
    const float* wk  = (const float*)d_in[5];
    const float* bk  = (const float*)d_in[6];
    const float* wv  = (const float*)d_in[7];
    const float* bv  = (const float*)d_in[8];
    const float* rpb = (const float*)d_in[9];
    const float* wo  = (const float*)d_in[10];
    const float* bo  = (const float*)d_in[11];

    const long P = 2l * 128 * 128;  // 32768 pixels
    unsigned short* qh = (unsigned short*)d_ws;
    unsigned short* kh = qh + P * 512;
    unsigned short* vh = kh + P * 512;
    unsigned short* xb = vh + P * 512;
    unsigned short* Wb = xb + P * 512;   // 4 x 512 x 512 bf16 (2 MB)

    const float scale = 0.17677669529663687f;  // 32^-0.5
    const size_t smem = 2 * 512 * 32 * 2;      // 64 KB (W double-buffer)

    cvt_w4<<<512, 256, 0, stream>>>(wq, wk, wv, wo, Wb);

    gemm_rA<true, false><<<512, 256, smem, stream>>>(q, Wb,          bq, qh, scale);
    gemm_rA<true, false><<<512, 256, smem, stream>>>(k, Wb + 262144, bk, kh, 1.0f);
    gemm_rA<true, false><<<512, 256, smem, stream>>>(v, Wb + 524288, bv, vh, 1.0f);

    natt<<<dim3(8, 8, 32), 256, 0, stream>>>(qh, kh, vh, rpb, xb);

    gemm_rA<false, true><<<512, 256, smem, stream>>>(xb, Wb + 786432, bo, (float*)d_out, 1.0f);
}

// Round 8
// 256.114 us; speedup vs baseline: 1.6873x; 1.6873x over previous
//
#include <hip/hip_runtime.h>
#include <hip/hip_bf16.h>

typedef __attribute__((ext_vector_type(8))) short          s16x8;
typedef __attribute__((ext_vector_type(8))) unsigned short u16x8;
typedef __attribute__((ext_vector_type(4))) float          f4;
typedef __attribute__((ext_vector_type(2))) float          f2;
typedef __attribute__((ext_vector_type(4))) unsigned int   u32x4;

__device__ __forceinline__ float bf2f(unsigned short u) {
    union { unsigned int i; float f; } x; x.i = ((unsigned int)u) << 16; return x.f;
}
__device__ __forceinline__ float blo(unsigned int w) {
    union { unsigned int i; float f; } x; x.i = w << 16; return x.f;
}
__device__ __forceinline__ float bhi(unsigned int w) {
    union { unsigned int i; float f; } x; x.i = w & 0xffff0000u; return x.f;
}
__device__ __forceinline__ unsigned short f2bf(float f) {
    __hip_bfloat16 h = __float2bfloat16(f);
    return *reinterpret_cast<unsigned short*>(&h);
}
__device__ __forceinline__ void gload_lds16(const void* g, void* l) {
    __builtin_amdgcn_global_load_lds(
        (const __attribute__((address_space(1))) unsigned int*)g,
        (__attribute__((address_space(3))) unsigned int*)l, 16, 0, 0);
}

// Convert the 4 weight matrices (each 512x512 fp32) to bf16, concatenated.
__global__ __launch_bounds__(256) void cvt_w4(const float* __restrict__ a,
                                              const float* __restrict__ b,
                                              const float* __restrict__ c,
                                              const float* __restrict__ d,
                                              unsigned short* __restrict__ o) {
    const int i   = (blockIdx.x * 256 + threadIdx.x) * 8;
    const int seg = i >> 18;
    const int off = i & 262143;
    const float* s = (seg == 0) ? a : (seg == 1) ? b : (seg == 2) ? c : d;
    f4 x0 = *(const f4*)(s + off);
    f4 x1 = *(const f4*)(s + off + 4);
    unsigned short t[8];
    t[0] = f2bf(x0[0]); t[1] = f2bf(x0[1]); t[2] = f2bf(x0[2]); t[3] = f2bf(x0[3]);
    t[4] = f2bf(x1[0]); t[5] = f2bf(x1[1]); t[6] = f2bf(x1[2]); t[7] = f2bf(x1[3]);
    *(u16x8*)(o + i) = *(u16x8*)t;
}

// OUT[m][n] = (sum_k A[m][k] * W[n][k] + bias[n]) * scale
// Round-6 gemm_fn, unchanged (best measured: ~37 us/GEMM). Full-N blocks,
// double-buffered dynamic LDS, BK=32, counted vmcnt with vmcnt(0) tail,
// both-sides XOR swizzle.
template <bool AF32, bool OF32>
__global__ __launch_bounds__(256, 2) void gemm_fn(const void* __restrict__ Ap,
                                                  const unsigned short* __restrict__ Wb,
                                                  const float* __restrict__ bias,
                                                  void* __restrict__ Outp,
                                                  float scale) {
    constexpr int KD = 512, BK = 32, NT = KD / BK;            // 16 K-tiles
    constexpr int ASZ = AF32 ? 64 * BK * 4 : 64 * BK * 2;     // 8 KB / 4 KB
    constexpr int WSZ = 512 * BK * 2;                          // 32 KB
    constexpr int STRIDE = ASZ + WSZ;
    extern __shared__ unsigned char lds[];                     // 2*STRIDE bytes

    const int tid  = threadIdx.x;
    const int lane = tid & 63;
    const int w    = tid >> 6;            // wave id 0..3 -> cols [w*128, w*128+128)
    const size_t m0 = (size_t)blockIdx.x * 64;

    const float*          Af = (const float*)Ap;
    const unsigned short* Ab = (const unsigned short*)Ap;

    const int fr = lane & 15;             // frag row (A) / col (B/D)
    const int j4 = lane >> 4;             // k-slot 0..3 (k = j4*8 + e)

    f4 acc[4][8];
#pragma unroll
    for (int i = 0; i < 4; ++i)
#pragma unroll
        for (int j = 0; j < 8; ++j) acc[i][j] = (f4)(0.0f);

    auto stage = [&](int t, int buf) {
        const int kt = t * BK;
        unsigned char* base = lds + buf * STRIDE;
        if constexpr (AF32) {
#pragma unroll
            for (int i = 0; i < 2; ++i) {
                const int f = i * 256 + tid;
                const int row = f >> 3, p = f & 7;
                const int s = p ^ (row & 7);
                gload_lds16(Af + (m0 + row) * KD + kt + s * 4, base + f * 16);
            }
        } else {
            const int f = tid;
            const int l = f ^ ((f >> 3) & 7);
            gload_lds16(Ab + (m0 + (l >> 2)) * KD + kt + (l & 3) * 8, base + f * 16);
        }
#pragma unroll
        for (int i = 0; i < 8; ++i) {
            const int f = i * 256 + tid;
            const int l = f ^ ((f >> 3) & 7);
            gload_lds16(Wb + (size_t)(l >> 2) * KD + kt + (l & 3) * 8,
                        base + ASZ + f * 16);
        }
    };

    stage(0, 0);
    stage(1, 1);

    for (int t = 0; t < NT; ++t) {
        const int buf = t & 1;
        unsigned char* base = lds + buf * STRIDE;
        if (t + 1 < NT) {
            if constexpr (AF32) asm volatile("s_waitcnt vmcnt(10)" ::: "memory");
            else                asm volatile("s_waitcnt vmcnt(9)"  ::: "memory");
        } else {
            asm volatile("s_waitcnt vmcnt(0)" ::: "memory");
        }
        __builtin_amdgcn_s_barrier();
        __builtin_amdgcn_sched_barrier(0);

        s16x8 af[4];
#pragma unroll
        for (int mi = 0; mi < 4; ++mi) {
            const int row = mi * 16 + fr;
            if constexpr (AF32) {
                const int r7 = row & 7;
                const int s0 = j4 * 2;
                f4 x0 = *(const f4*)(base + row * 128 + ((s0 ^ r7) << 4));
                f4 x1 = *(const f4*)(base + row * 128 + (((s0 + 1) ^ r7) << 4));
                unsigned short u[8];
                u[0] = f2bf(x0[0]); u[1] = f2bf(x0[1]); u[2] = f2bf(x0[2]); u[3] = f2bf(x0[3]);
                u[4] = f2bf(x1[0]); u[5] = f2bf(x1[1]); u[6] = f2bf(x1[2]); u[7] = f2bf(x1[3]);
                af[mi] = *(s16x8*)u;
            } else {
                const int L = (row << 2) | j4;
                const int P = L ^ ((L >> 3) & 7);
                af[mi] = *(const s16x8*)(base + (P << 4));
            }
        }
#pragma unroll
        for (int ni = 0; ni < 8; ++ni) {
            const int nrow = w * 128 + ni * 16 + fr;
            const int L = (nrow << 2) | j4;
            const int P = L ^ ((L >> 3) & 7);
            const s16x8 bf = *(const s16x8*)(base + ASZ + (P << 4));
#pragma unroll
            for (int mi = 0; mi < 4; ++mi)
                acc[mi][ni] = __builtin_amdgcn_mfma_f32_16x16x32_bf16(
                    af[mi], bf, acc[mi][ni], 0, 0, 0);
        }

        __builtin_amdgcn_sched_barrier(0);
        __builtin_amdgcn_s_barrier();
        __builtin_amdgcn_sched_barrier(0);
        if (t + 2 < NT) stage(t + 2, buf);
    }

    const int rq = (lane >> 4) << 2;
#pragma unroll
    for (int ni = 0; ni < 8; ++ni) {
        const int   col = w * 128 + ni * 16 + fr;
        const float bv  = bias[col];
#pragma unroll
        for (int mi = 0; mi < 4; ++mi) {
            const size_t rbase = m0 + mi * 16 + rq;
#pragma unroll
            for (int r = 0; r < 4; ++r) {
                const float val = (acc[mi][ni][r] + bv) * scale;
                if constexpr (OF32)
                    ((float*)Outp)[(rbase + r) * KD + col] = val;
                else
                    ((unsigned short*)Outp)[(rbase + r) * KD + col] = f2bf(val);
            }
        }
    }
}

// LDS-tiled NAT (round-6 structure; inner loops use packed f32 math).
// __launch_bounds__(256,4) pins VGPR <= 128 (round-7 lesson: occupancy is
// the binding resource here, not dep chains).
__global__ __launch_bounds__(256, 4) void natt(const unsigned short* __restrict__ qh,
                                               const unsigned short* __restrict__ kh,
                                               const unsigned short* __restrict__ vh,
                                               const float* __restrict__ rpb,
                                               unsigned short* __restrict__ xout) {
    constexpr int LDK = 40;
    __shared__ unsigned short KV[484][LDK];
    __shared__ float Rs[169];

    const int tid = threadIdx.x;
    const int h   = blockIdx.z & 15;
    const int b   = blockIdx.z >> 4;
    const int x0  = blockIdx.x * 16;
    const int y0  = blockIdx.y * 16;
    const int ux0 = min(max(x0 - 3, 0), 106);
    const int uy0 = min(max(y0 - 3, 0), 106);
    const int tx  = tid & 15;
    const int ty  = tid >> 4;
    const int x   = x0 + tx;
    const int y   = y0 + ty;

    if (tid < 169) Rs[tid] = rpb[h * 169 + tid];

    const long imgbase = (long)b * 128 * 128;

#pragma unroll 2
    for (int kk = tid; kk < 484; kk += 256) {
        const int ky = uy0 + kk / 22;
        const int kx = ux0 + kk % 22;
        const unsigned short* src = kh + (imgbase + ky * 128 + kx) * 512 + h * 32;
#pragma unroll
        for (int j = 0; j < 4; ++j)
            *(u16x8*)&KV[kk][j * 8] = *(const u16x8*)(src + j * 8);
    }

    const long pix = imgbase + y * 128 + x;
    const unsigned short* qp = qh + pix * 512 + h * 32;
    f2 qv[16];
#pragma unroll
    for (int j = 0; j < 4; ++j) {
        u16x8 v = *(const u16x8*)(qp + j * 8);
#pragma unroll
        for (int e = 0; e < 4; ++e)
            qv[j * 4 + e] = (f2){bf2f(v[2 * e]), bf2f(v[2 * e + 1])};
    }

    const int myy = min(max(y - 3, 0), 121) - uy0;
    const int myx = min(max(x - 3, 0), 121) - ux0;
    const int pbY = (y < 3) ? (6 - y) : ((y >= 125) ? (127 - y) : 3);
    const int pbX = (x < 3) ? (6 - x) : ((x >= 125) ? (127 - x) : 3);

    __syncthreads();

    float logit[49];
#pragma unroll
    for (int a = 0; a < 7; ++a) {
        const int rowk = (myy + a) * 22 + myx;
#pragma unroll
        for (int c = 0; c < 7; ++c) {
            const u32x4* kp = (const u32x4*)&KV[rowk + c][0];
            f2 sA = {0.f, 0.f}, sB = {0.f, 0.f};
#pragma unroll
            for (int j = 0; j < 4; ++j) {
                const u32x4 w = kp[j];
                sA += qv[4 * j + 0] * (f2){blo(w[0]), bhi(w[0])};
                sB += qv[4 * j + 1] * (f2){blo(w[1]), bhi(w[1])};
                sA += qv[4 * j + 2] * (f2){blo(w[2]), bhi(w[2])};
                sB += qv[4 * j + 3] * (f2){blo(w[3]), bhi(w[3])};
            }
            logit[a * 7 + c] = (sA[0] + sA[1]) + (sB[0] + sB[1])
                             + Rs[(pbY + a) * 13 + pbX + c];
        }
    }

    float m = logit[0];
#pragma unroll
    for (int i = 1; i < 49; ++i) m = fmaxf(m, logit[i]);
    float sum = 0.f;
#pragma unroll
    for (int i = 0; i < 49; ++i) {
        float p = exp2f((logit[i] - m) * 1.4426950408889634f);
        logit[i] = p;
        sum += p;
    }
    const float rinv = 1.f / sum;
#pragma unroll
    for (int i = 0; i < 49; ++i) logit[i] *= rinv;

    __syncthreads();

#pragma unroll 2
    for (int kk = tid; kk < 484; kk += 256) {
        const int ky = uy0 + kk / 22;
        const int kx = ux0 + kk % 22;
        const unsigned short* src = vh + (imgbase + ky * 128 + kx) * 512 + h * 32;
#pragma unroll
        for (int j = 0; j < 4; ++j)
            *(u16x8*)&KV[kk][j * 8] = *(const u16x8*)(src + j * 8);
    }
    __syncthreads();

    f2 acc2[16];
#pragma unroll
    for (int d = 0; d < 16; ++d) acc2[d] = (f2){0.f, 0.f};
#pragma unroll
    for (int a = 0; a < 7; ++a) {
        const int rowk = (myy + a) * 22 + myx;
#pragma unroll
        for (int c = 0; c < 7; ++c) {
            const u32x4* vp = (const u32x4*)&KV[rowk + c][0];
            const float wgt = logit[a * 7 + c];
            const f2 w2 = {wgt, wgt};
#pragma unroll
            for (int j = 0; j < 4; ++j) {
                const u32x4 w = vp[j];
                acc2[4 * j + 0] += w2 * (f2){blo(w[0]), bhi(w[0])};
                acc2[4 * j + 1] += w2 * (f2){blo(w[1]), bhi(w[1])};
                acc2[4 * j + 2] += w2 * (f2){blo(w[2]), bhi(w[2])};
                acc2[4 * j + 3] += w2 * (f2){blo(w[3]), bhi(w[3])};
            }
        }
    }

    unsigned short* op = xout + pix * 512 + h * 32;
#pragma unroll
    for (int j = 0; j < 4; ++j) {
        unsigned short t[8];
#pragma unroll
        for (int e = 0; e < 4; ++e) {
            t[2 * e]     = f2bf(acc2[j * 4 + e][0]);
            t[2 * e + 1] = f2bf(acc2[j * 4 + e][1]);
        }
        *(u16x8*)(op + j * 8) = *(u16x8*)t;
    }
}

extern "C" void kernel_launch(void* const* d_in, const int* in_sizes, int n_in,
                              void* d_out, int out_size, void* d_ws, size_t ws_size,
                              hipStream_t stream) {
    const float* q   = (const float*)d_in[0];
    const float* k   = (const float*)d_in[1];
    const float* v   = (const float*)d_in[2];
    const float* wq  = (const float*)d_in[3];
    const float* bq  = (const float*)d_in[4];
    const float* wk  = (const float*)d_in[5];
    const float* bk  = (const float*)d_in[6];
    const float* wv  = (const float*)d_in[7];
    const float* bv  = (const float*)d_in[8];
    const float* rpb = (const float*)d_in[9];
    const float* wo  = (const float*)d_in[10];
    const float* bo  = (const float*)d_in[11];

    const long P = 2l * 128 * 128;  // 32768 pixels
    unsigned short* qh = (unsigned short*)d_ws;
    unsigned short* kh = qh + P * 512;
    unsigned short* vh = kh + P * 512;
    unsigned short* xb = vh + P * 512;
    unsigned short* Wb = xb + P * 512;   // 4 x 512 x 512 bf16 (2 MB)

    const float scale = 0.17677669529663687f;  // 32^-0.5
    const size_t smemF = 2 * (64 * 32 * 4 + 512 * 32 * 2);  // 81920
    const size_t smemB = 2 * (64 * 32 * 2 + 512 * 32 * 2);  // 73728

    cvt_w4<<<512, 256, 0, stream>>>(wq, wk, wv, wo, Wb);

    gemm_fn<true, false><<<512, 256, smemF, stream>>>(q, Wb,          bq, qh, scale);
    gemm_fn<true, false><<<512, 256, smemF, stream>>>(k, Wb + 262144, bk, kh, 1.0f);
    gemm_fn<true, false><<<512, 256, smemF, stream>>>(v, Wb + 524288, bv, vh, 1.0f);

    natt<<<dim3(8, 8, 32), 256, 0, stream>>>(qh, kh, vh, rpb, xb);

    gemm_fn<false, true><<<512, 256, smemB, stream>>>(xb, Wb + 786432, bo, (float*)d_out, 1.0f);
}